// Round 1
// baseline (2904.882 us; speedup 1.0000x reference)
//
#include <hip/hip_runtime.h>
#include <math.h>

typedef float f4 __attribute__((ext_vector_type(4)));

#define NNODES 50000
#define NEDGES 1600000
#define WROW 160   // floats per k-row of padded transposed weights: 8 chunks x (16+4)

// ---------------- kernel 1: vl = v @ lin_w^T  (50000x128 @ 128x128) ----------------
__global__ __launch_bounds__(512, 2) void vl_kernel(
    const float* __restrict__ v, const float* __restrict__ lin_w,
    float* __restrict__ vl) {
  __shared__ float wT[128 * WROW];   // 80 KB, [k][chunk g][16 floats + 4 pad]
  __shared__ float vt[64 * 132];     // 33.8 KB, padded rows
  const int tid = threadIdx.x;
  const int g = tid & 7;             // col chunk: cols g*16 .. g*16+15
  const int s = tid >> 3;            // node slot in tile, [0,64)

  // stage lin_w transposed into padded layout (coalesced global reads)
  for (int idx = tid; idx < 128 * 128; idx += 512) {
    const int f = idx >> 7, k = idx & 127;
    wT[k * WROW + (f >> 4) * 20 + (f & 15)] = lin_w[idx];
  }
  // stage v tile
  const int base = blockIdx.x * 64;
  for (int idx = tid; idx < 64 * 32; idx += 512) {
    const int row = idx >> 5, c4 = (idx & 31) << 2;
    const int n = base + row;
    f4 val = {0.f, 0.f, 0.f, 0.f};
    if (n < NNODES) val = *(const f4*)&v[(size_t)n * 128 + c4];
    *(f4*)&vt[row * 132 + c4] = val;
  }
  __syncthreads();

  f4 a0 = {0.f,0.f,0.f,0.f}, a1 = a0, a2 = a0, a3 = a0;
  const float* wbase = &wT[g * 20];
  #pragma unroll 2
  for (int k = 0; k < 128; ++k) {
    const float a = vt[s * 132 + k];
    const f4* w = (const f4*)&wbase[k * WROW];
    a0 += w[0] * a; a1 += w[1] * a; a2 += w[2] * a; a3 += w[3] * a;
  }
  const int n = base + s;
  if (n < NNODES) {
    float* o = &vl[(size_t)n * 128 + g * 16];
    *(f4*)&o[0] = a0; *(f4*)&o[4] = a1; *(f4*)&o[8] = a2; *(f4*)&o[12] = a3;
  }
}

// ---------------- kernel 2: per-edge filter + gather + multiply ----------------
__device__ __forceinline__ float softplus_shift(float x) {
  // jax.nn.softplus(x) - log(2):  max(x,0) + log1p(exp(-|x|)) - 0.69314718
  return fmaxf(x, 0.f) + log1pf(expf(-fabsf(x))) - 0.69314718056f;
}

__global__ __launch_bounds__(512, 2) void edge_kernel(
    const float* __restrict__ dist, const float* __restrict__ demb,
    const int* __restrict__ eidx, const float* __restrict__ m1w,
    const float* __restrict__ m1b, const float* __restrict__ m2w,
    const float* __restrict__ m2b, const float* __restrict__ vl,
    float* __restrict__ out) {
  __shared__ float w1T[50 * WROW];    // 32000 B
  __shared__ float w2T[128 * WROW];   // 81920 B
  __shared__ float hbuf[64 * 132];    // 33792 B
  __shared__ float dbuf[64 * 50];     // 12800 B  -> total 160512 B

  const int tid = threadIdx.x;
  const int g = tid & 7;              // col chunk
  const int s = tid >> 3;             // edge slot in tile, [0,64)

  // stage both MLP weights transposed+padded (once per block)
  for (int idx = tid; idx < 128 * 50; idx += 512) {
    const int f = idx / 50, k = idx - f * 50;     // coalesced over idx
    w1T[k * WROW + (f >> 4) * 20 + (f & 15)] = m1w[idx];
  }
  for (int idx = tid; idx < 128 * 128; idx += 512) {
    const int f = idx >> 7, k = idx & 127;
    w2T[k * WROW + (f >> 4) * 20 + (f & 15)] = m2w[idx];
  }
  // per-thread biases (cols fixed per thread)
  f4 b1r[4], b2r[4];
  #pragma unroll
  for (int q = 0; q < 4; ++q) {
    b1r[q] = *(const f4*)&m1b[g * 16 + q * 4];
    b2r[q] = *(const f4*)&m2b[g * 16 + q * 4];
  }

  const int tiles = NEDGES / 64;   // 25000
  for (int t = blockIdx.x; t < tiles; t += gridDim.x) {
    __syncthreads();   // previous tile fully consumed (dbuf/hbuf reusable)
    // stage dist_emb tile (contiguous 3200 floats)
    for (int idx = tid; idx < 800; idx += 512) {
      *(f4*)&dbuf[idx * 4] = *(const f4*)&demb[(size_t)t * 3200 + idx * 4];
    }
    __syncthreads();

    const int e = t * 64 + s;

    // phase 1: h = softplus(demb @ W1^T + b1) - shift   (K = 50)
    f4 c0 = b1r[0], c1 = b1r[1], c2 = b1r[2], c3 = b1r[3];
    const float* w1base = &w1T[g * 20];
    #pragma unroll 2
    for (int k = 0; k < 50; ++k) {
      const float d = dbuf[s * 50 + k];
      const f4* w = (const f4*)&w1base[k * WROW];
      c0 += w[0] * d; c1 += w[1] * d; c2 += w[2] * d; c3 += w[3] * d;
    }
    {
      f4 r;
      float* hrow = &hbuf[s * 132 + g * 16];
      r[0]=softplus_shift(c0[0]); r[1]=softplus_shift(c0[1]); r[2]=softplus_shift(c0[2]); r[3]=softplus_shift(c0[3]);
      *(f4*)&hrow[0] = r;
      r[0]=softplus_shift(c1[0]); r[1]=softplus_shift(c1[1]); r[2]=softplus_shift(c1[2]); r[3]=softplus_shift(c1[3]);
      *(f4*)&hrow[4] = r;
      r[0]=softplus_shift(c2[0]); r[1]=softplus_shift(c2[1]); r[2]=softplus_shift(c2[2]); r[3]=softplus_shift(c2[3]);
      *(f4*)&hrow[8] = r;
      r[0]=softplus_shift(c3[0]); r[1]=softplus_shift(c3[1]); r[2]=softplus_shift(c3[2]); r[3]=softplus_shift(c3[3]);
      *(f4*)&hrow[12] = r;
    }
    __syncthreads();

    // phase 2: W = (h @ W2^T + b2) * C   (K = 128)
    f4 a0 = b2r[0], a1 = b2r[1], a2 = b2r[2], a3 = b2r[3];
    const float* w2base = &w2T[g * 20];
    #pragma unroll 2
    for (int k = 0; k < 128; ++k) {
      const float h = hbuf[s * 132 + k];
      const f4* w = (const f4*)&w2base[k * WROW];
      a0 += w[0] * h; a1 += w[1] * h; a2 += w[2] * h; a3 += w[3] * h;
    }

    // epilogue: e_out = vl[j] * W * C
    const float dv = dist[e];
    const float C = 0.5f * (cosf(dv * 0.31415927f) + 1.0f);
    const int j = eidx[e];
    const float* vr = &vl[(size_t)j * 128 + g * 16];
    float* orow = &out[(size_t)e * 128 + g * 16];
    const f4 v0 = *(const f4*)&vr[0], v1 = *(const f4*)&vr[4],
             v2 = *(const f4*)&vr[8], v3 = *(const f4*)&vr[12];
    *(f4*)&orow[0]  = a0 * C * v0;
    *(f4*)&orow[4]  = a1 * C * v1;
    *(f4*)&orow[8]  = a2 * C * v2;
    *(f4*)&orow[12] = a3 * C * v3;
  }
}

extern "C" void kernel_launch(void* const* d_in, const int* in_sizes, int n_in,
                              void* d_out, int out_size, void* d_ws, size_t ws_size,
                              hipStream_t stream) {
  const float* v     = (const float*)d_in[0];
  const float* dist  = (const float*)d_in[1];
  const float* demb  = (const float*)d_in[2];
  const int*   eidx  = (const int*)d_in[3];   // edge_index[0] = first E elements
  const float* lin_w = (const float*)d_in[4];
  const float* m1w   = (const float*)d_in[5];
  const float* m1b   = (const float*)d_in[6];
  const float* m2w   = (const float*)d_in[7];
  const float* m2b   = (const float*)d_in[8];
  float* out = (float*)d_out;
  float* vl  = (float*)d_ws;                  // 50000*128 f32 = 25.6 MB scratch

  vl_kernel<<<(NNODES + 63) / 64, 512, 0, stream>>>(v, lin_w, vl);
  edge_kernel<<<256, 512, 0, stream>>>(dist, demb, eidx, m1w, m1b, m2w, m2b, vl, out);
}